// Round 1
// baseline (42.297 us; speedup 1.0000x reference)
//
#include <hip/hip_runtime.h>

// RandomResizedCropPair: bilinear crop-resize (image) + nearest crop-resize (mask)
// image: [32,3,512,512] f32, mask: [32,1,512,512] f32
// crop_size/top/left: [32] i32
// out: img [32,3,384,384] f32 ++ msk [32,1,384,384] f32

constexpr int OUT = 384;
constexpr int H = 512;
constexpr int W = 512;
constexpr int B = 32;
constexpr int C = 3;

__global__ __launch_bounds__(256) void rrc_pair_kernel(
    const float* __restrict__ image,
    const float* __restrict__ mask,
    const int* __restrict__ crop_size,
    const int* __restrict__ top,
    const int* __restrict__ left,
    float* __restrict__ img_out,
    float* __restrict__ msk_out)
{
    int tid = blockIdx.x * blockDim.x + threadIdx.x;
    if (tid >= B * OUT * OUT) return;
    int j = tid % OUT;
    int rest = tid / OUT;
    int i = rest % OUT;
    int b = rest / OUT;

    const int cs = crop_size[b];
    const int t  = top[b];
    const int l  = left[b];
    const float csf = (float)cs;
    const float s   = csf / (float)OUT;   // match reference: csf/SIZE computed first

    // --- bilinear y (PyTorch align_corners=False semantics) ---
    float cy = ((float)i + 0.5f) * s - 0.5f;
    cy = fminf(fmaxf(cy, 0.0f), csf - 1.0f);
    int   iy0 = (int)floorf(cy);
    int   iy1 = min(iy0 + 1, cs - 1);
    float wy  = cy - (float)iy0;

    // --- bilinear x ---
    float cx = ((float)j + 0.5f) * s - 0.5f;
    cx = fminf(fmaxf(cx, 0.0f), csf - 1.0f);
    int   ix0 = (int)floorf(cx);
    int   ix1 = min(ix0 + 1, cs - 1);
    float wx  = cx - (float)ix0;

    const int y0 = iy0 + t, y1 = iy1 + t;
    const int x0 = ix0 + l, x1 = ix1 + l;

    const float w00 = (1.0f - wy) * (1.0f - wx);
    const float w01 = (1.0f - wy) * wx;
    const float w10 = wy * (1.0f - wx);
    const float w11 = wy * wx;

    const float* imgb = image + (size_t)b * C * H * W;
    const size_t o_base = (size_t)b * C * OUT * OUT + (size_t)i * OUT + (size_t)j;

    #pragma unroll
    for (int c = 0; c < C; ++c) {
        const float* p = imgb + (size_t)c * H * W;
        float v00 = p[(size_t)y0 * W + x0];
        float v01 = p[(size_t)y0 * W + x1];
        float v10 = p[(size_t)y1 * W + x0];
        float v11 = p[(size_t)y1 * W + x1];
        img_out[o_base + (size_t)c * OUT * OUT] =
            v00 * w00 + v01 * w01 + v10 * w10 + v11 * w11;
    }

    // --- nearest mask: src = floor(dst * cs / OUT), exact via integer div ---
    int my = (i * cs) / OUT; my = min(my, cs - 1);
    int mx = (j * cs) / OUT; mx = min(mx, cs - 1);
    msk_out[((size_t)b * OUT + i) * OUT + j] =
        mask[((size_t)b * H + (my + t)) * W + (mx + l)];
}

extern "C" void kernel_launch(void* const* d_in, const int* in_sizes, int n_in,
                              void* d_out, int out_size, void* d_ws, size_t ws_size,
                              hipStream_t stream) {
    const float* image = (const float*)d_in[0];
    const float* mask  = (const float*)d_in[1];
    const int* cs      = (const int*)d_in[2];
    const int* top     = (const int*)d_in[3];
    const int* left    = (const int*)d_in[4];

    float* img_out = (float*)d_out;
    float* msk_out = img_out + (size_t)B * C * OUT * OUT;

    const int total = B * OUT * OUT;
    dim3 block(256);
    dim3 grid((total + 255) / 256);
    hipLaunchKernelGGL(rrc_pair_kernel, grid, block, 0, stream,
                       image, mask, cs, top, left, img_out, msk_out);
}